// Round 3
// baseline (379.222 us; speedup 1.0000x reference)
//
#include <hip/hip_runtime.h>

// ---------------------------------------------------------------------------
// MultiDiscreteACTLayer: B=131072 rows, D=256.
// Per row: 8 users x 16 sc logits + 8 heads x 10 pow logits = 208 dots of 256.
// JAX threefry, PARTITIONABLE semantics (jax>=0.4.36 default):
//   split(key,8)[u] = threefry2x32(key, (0, u))          (foldlike, both words)
//   fold_in(key, d) = threefry2x32(key, (0, d))          (both words)
//   random_bits 32-bit, element i: (b1,b2)=tf2(key,(0,i)); bits = b1 ^ b2
// Output (float32): actions (B,16) | logp_sum (B,1) | avail (B,16).
// R11 (from R10): occupancy 2 -> 3 blocks/CU.
//   - LDS 77.3KB -> 50.7KB: logit writes deferred past the xb-dead barrier;
//     gpow[32][80] + lgT[208][36] alias the x-limb slab. Accumulators
//     (accM+accS combined to one f32x4 per tile-half) held across barrier.
//   - Logits stored TRANSPOSED via ds_write_b128: C-fragment lane holds a
//     column of 4 consecutive rows -> 1 b128 store per tile-half; store
//     quad-banks (jo+q)%8 perfectly spread; Phase C reads lgT[col][row]
//     are exactly 2-way (free). Removes R10's 4-way lg bank conflict.
//   - __launch_bounds__(512,6) pins VGPR <= ~85 for 24 waves/CU.
//   GEMM numerics (bf16 3-limb), fp64 gumbel, Phase C DPP trees unchanged.
// ---------------------------------------------------------------------------

#define B_TOTAL 131072
#define NCOL    208      // 8 users * (16 sc + 10 pow)
#define ROWS    32       // rows per block
#define TINYF   1.17549435e-38f

// W limb plane geometry (shorts): per (tile,chunk) 512, per tile 8*512=4096,
// per plane 13*4096 = 53248. Three planes.
#define WPLANE  53248
#define XB_L    8448     // x limb stride in shorts: 32 rows * 264 pitch
#define XB_P    264      // x row pitch in shorts (16B-aligned, bank-spread)
#define LGP     36       // lgT row pitch in floats (32 rows + pad)

typedef float f32x4 __attribute__((ext_vector_type(4)));
typedef short short8 __attribute__((ext_vector_type(8)));

#define MFMA_BF16(A,B,C) __builtin_amdgcn_mfma_f32_16x16x32_bf16((A),(B),(C),0,0,0)

// DPP row_ror within 16-lane rows (gfx9+ DPP row = 16 lanes).
// ctrl 0x120|n = row_ror:n. Full exec everywhere -> bound_ctrl false, old=src.
#define ROR16(v, n) __uint_as_float((unsigned)__builtin_amdgcn_update_dpp(     \
    (int)__float_as_uint(v), (int)__float_as_uint(v), 0x120 | (n), 0xF, 0xF, false))

__device__ __forceinline__ float redmax16(float v) {
  v = fmaxf(v, ROR16(v, 8));
  v = fmaxf(v, ROR16(v, 4));
  v = fmaxf(v, ROR16(v, 2));
  v = fmaxf(v, ROR16(v, 1));
  return v;
}
__device__ __forceinline__ float redsum16(float v) {
  v += ROR16(v, 8);
  v += ROR16(v, 4);
  v += ROR16(v, 2);
  v += ROR16(v, 1);
  return v;
}

struct TF2 { unsigned a, b; };

__host__ __device__ constexpr unsigned rotl_(unsigned x, int r) {
  return (x << r) | (x >> (32 - r));
}

// Threefry-2x32, 20 rounds, exactly as JAX/Random123.
__host__ __device__ constexpr TF2 tf2(unsigned k0, unsigned k1, unsigned x0, unsigned x1) {
  unsigned ks0 = k0, ks1 = k1, ks2 = k0 ^ k1 ^ 0x1BD11BDAu;
  x0 += ks0; x1 += ks1;
  x0 += x1; x1 = rotl_(x1, 13); x1 ^= x0;
  x0 += x1; x1 = rotl_(x1, 15); x1 ^= x0;
  x0 += x1; x1 = rotl_(x1, 26); x1 ^= x0;
  x0 += x1; x1 = rotl_(x1,  6); x1 ^= x0;
  x0 += ks1; x1 += ks2 + 1u;
  x0 += x1; x1 = rotl_(x1, 17); x1 ^= x0;
  x0 += x1; x1 = rotl_(x1, 29); x1 ^= x0;
  x0 += x1; x1 = rotl_(x1, 16); x1 ^= x0;
  x0 += x1; x1 = rotl_(x1, 24); x1 ^= x0;
  x0 += ks2; x1 += ks0 + 2u;
  x0 += x1; x1 = rotl_(x1, 13); x1 ^= x0;
  x0 += x1; x1 = rotl_(x1, 15); x1 ^= x0;
  x0 += x1; x1 = rotl_(x1, 26); x1 ^= x0;
  x0 += x1; x1 = rotl_(x1,  6); x1 ^= x0;
  x0 += ks0; x1 += ks1 + 3u;
  x0 += x1; x1 = rotl_(x1, 17); x1 ^= x0;
  x0 += x1; x1 = rotl_(x1, 29); x1 ^= x0;
  x0 += x1; x1 = rotl_(x1, 16); x1 ^= x0;
  x0 += x1; x1 = rotl_(x1, 24); x1 ^= x0;
  x0 += ks1; x1 += ks2 + 4u;
  x0 += x1; x1 = rotl_(x1, 13); x1 ^= x0;
  x0 += x1; x1 = rotl_(x1, 15); x1 ^= x0;
  x0 += x1; x1 = rotl_(x1, 26); x1 ^= x0;
  x0 += x1; x1 = rotl_(x1,  6); x1 ^= x0;
  x0 += ks2; x1 += ks0 + 5u;
  return TF2{x0, x1};
}

// foldlike derivation from root key (0, 42) — all compile-time constants.
__host__ __device__ constexpr unsigned key_a(unsigned d) { return tf2(0u, 42u, 0u, d).a; }
__host__ __device__ constexpr unsigned key_b(unsigned d) { return tf2(0u, 42u, 0u, d).b; }

constexpr unsigned SK0c[8] = {
  key_a(0), key_a(1), key_a(2), key_a(3), key_a(4), key_a(5), key_a(6), key_a(7)
};
constexpr unsigned SK1c[8] = {
  key_b(0), key_b(1), key_b(2), key_b(3), key_b(4), key_b(5), key_b(6), key_b(7)
};
constexpr unsigned PK0 = key_a(999);
constexpr unsigned PK1 = key_b(999);

// Fast fp64 natural log, positive normal inputs. Range-reduce m to
// [sqrt(1/2), sqrt(2)); atanh series in z=(m-1)/(m+1), terms to 1/13
// (trunc ~3e-12 rel); reciprocal via rcp_f32 seed + 1 fp64 Newton
// (~1.4e-14 rel). Total err ~1e-12 — flip-probability analysis: safe.
__device__ __forceinline__ double dlog(double xd) {
  long long b = __double_as_longlong(xd);
  int e = (int)(b >> 52) - 1023;
  double m = __longlong_as_double((b & 0x000FFFFFFFFFFFFFLL) | 0x3FF0000000000000LL);
  if (m > 1.4142135623730951) { m *= 0.5; e += 1; }
  double mp1 = m + 1.0;
  double r = (double)__builtin_amdgcn_rcpf((float)mp1);
  r = fma(fma(-mp1, r, 1.0), r, r);          // 1 Newton: ~1.4e-14 rel
  double z  = (m - 1.0) * r;
  double z2 = z * z;
  double p = fma(z2, fma(z2, fma(z2, fma(z2, fma(z2,
              1.0/13.0, 1.0/11.0), 1.0/9.0), 1.0/7.0), 1.0/5.0), 1.0/3.0);
  double lm = fma(2.0 * z, z2 * p, 2.0 * z);
  return fma((double)e, 0.6931471805599453, lm);
}

// JAX gumbel from raw bits, fp32 bit-ops replicated; logs in fp64 (dlog).
__device__ __forceinline__ float gumbelf(unsigned bits) {
  float u = __uint_as_float((bits >> 9) | 0x3f800000u) - 1.0f;   // [0,1)
  u = u + TINYF;
  u = fmaxf(TINYF, u);
  double nl = -dlog((double)u);            // in (5.9e-8, 87.4] — normal
  return -(float)dlog(nl);
}

// ---------------------------------------------------------------------------
// Kernel 0: split W_sc (8,256,16) + W_pow (8,256,10) into 3 bf16 limb planes,
// fragment-ordered for the act kernel's per-lane dwordx4 loads:
//   plane l, short index (T*8 + c)*512 + lane*8 + j  holds limb_l of
//   W[k = c*32 + (lane>>4)*8 + j][col = T*16 + (lane&15)],  col = u*26 + n.
// Truncation split: w = l0 + l1 + l2 exactly (fp32 = 3x8 mantissa bits).
// Plus packed bias bp[256] (fp32).
// ---------------------------------------------------------------------------
__global__ void repack_kernel(const float* __restrict__ Wsc, const float* __restrict__ bsc,
                              const float* __restrict__ Wpow, const float* __restrict__ bpow,
                              short* __restrict__ Wb, float* __restrict__ bp) {
  int t = blockIdx.x * 256 + threadIdx.x;   // [0, 53504)
  if (t < 53248) {
    int j    = t & 7;
    int lane = (t >> 3) & 63;
    int c    = (t >> 9) & 7;
    int T    = t >> 12;                     // 0..12
    int k    = c * 32 + (lane >> 4) * 8 + j;
    int col  = T * 16 + (lane & 15);        // < 208
    int u = col / 26, n = col % 26;
    float w = (n < 16) ? Wsc[(u * 256 + k) * 16 + n]
                       : Wpow[(u * 256 + k) * 10 + (n - 16)];
    unsigned b0 = __float_as_uint(w) & 0xFFFF0000u;
    float f1 = w - __uint_as_float(b0);
    unsigned b1 = __float_as_uint(f1) & 0xFFFF0000u;
    float f2 = f1 - __uint_as_float(b1);
    unsigned b2 = __float_as_uint(f2) & 0xFFFF0000u;
    int idx = (T * 8 + c) * 512 + lane * 8 + j;
    Wb[idx]              = (short)(b0 >> 16);
    Wb[WPLANE + idx]     = (short)(b1 >> 16);
    Wb[2 * WPLANE + idx] = (short)(b2 >> 16);
  } else {
    int cc = t - 53248;                     // [0,256)
    float v = 0.f;
    if (cc < NCOL) {
      int u = cc / 26, n = cc % 26;
      v = (n < 16) ? bsc[u * 16 + n] : bpow[u * 10 + (n - 16)];
    }
    bp[cc] = v;
  }
}

// 8 limb products (drop x2*W2 ~2^-32): accM = x0W0, accS = 7 small terms.
#define PROD8(X0, X1, X2, W0, W1, W2, AM, AS) do {                      \
    AM = MFMA_BF16(X0, W0, AM);                                         \
    AS = MFMA_BF16(X1, W0, AS);                                         \
    AS = MFMA_BF16(X0, W1, AS);                                         \
    AS = MFMA_BF16(X1, W1, AS);                                         \
    AS = MFMA_BF16(X2, W0, AS);                                         \
    AS = MFMA_BF16(X0, W2, AS);                                         \
    AS = MFMA_BF16(X2, W1, AS);                                         \
    AS = MFMA_BF16(X1, W2, AS);                                         \
  } while (0)

// ---------------------------------------------------------------------------
// Main kernel: each block handles 32 consecutive rows, 512 threads / 8 waves.
// Phase A: bf16 MFMA 16x16x32, 3-limb lossless split. Wave wv owns col-tile
//          tA=(wv+blk)&7 and (if tA<5) tB=8+tA; computes BOTH row-halves per
//          tile. C/D labels via runtime MFMA probes; accs combined and held
//          across the xb-dead barrier.
// Phase B: lgT b128 stores + pow gumbels into the re-used x-limb slab;
//          sc gumbels straight into registers.
// Phase C: 16 lanes per row; DPP row_ror reduce trees; ballot argmax;
//          avail as one ballot bitmask; no-max-shift softmax (fp32 hw).
// ---------------------------------------------------------------------------
__global__ __launch_bounds__(512, 6) void act_kernel(
    const float* __restrict__ x, const int* __restrict__ avail,
    const short* __restrict__ Wb, const float* __restrict__ bp,
    float* __restrict__ out) {
  __shared__ __align__(16) union SMem {
    short xb[3][ROWS][XB_P];     // Phase A: bf16 limbs of x tile (50688 B)
    struct {
      float gpow[ROWS][80];      // pow gumbels (10240 B)
      float lgT[NCOL][LGP];      // logits, TRANSPOSED [col][row] (29952 B)
    } c;
  } sm;

  const int t = threadIdx.x;
  const int b0 = blockIdx.x * ROWS;

  // ---- load x tile (32 rows x 256) as float4, split into bf16 limbs ----
#pragma unroll
  for (int i = 0; i < 4; ++i) {
    int flat = t + 512 * i;            // float4 index, [0,2048)
    int r  = flat >> 6;                // 64 float4 per row
    int kq = flat & 63;
    float4 v = ((const float4*)(x + (size_t)(b0 + r) * 256))[kq];
    unsigned L0[4], L1[4], L2[4];
#pragma unroll
    for (int e = 0; e < 4; ++e) {
      float f = (&v.x)[e];
      unsigned h0 = __float_as_uint(f) & 0xFFFF0000u;
      float f1 = f - __uint_as_float(h0);
      unsigned h1 = __float_as_uint(f1) & 0xFFFF0000u;
      float f2 = f1 - __uint_as_float(h1);
      unsigned h2 = __float_as_uint(f2) & 0xFFFF0000u;
      L0[e] = h0; L1[e] = h1; L2[e] = h2;
    }
    int ks = 4 * kq;
    *(uint2*)&sm.xb[0][r][ks] =
        make_uint2((L0[0] >> 16) | (L0[1] & 0xFFFF0000u),
                   (L0[2] >> 16) | (L0[3] & 0xFFFF0000u));
    *(uint2*)&sm.xb[1][r][ks] =
        make_uint2((L1[0] >> 16) | (L1[1] & 0xFFFF0000u),
                   (L1[2] >> 16) | (L1[3] & 0xFFFF0000u));
    *(uint2*)&sm.xb[2][r][ks] =
        make_uint2((L2[0] >> 16) | (L2[1] & 0xFFFF0000u),
                   (L2[2] >> 16) | (L2[3] & 0xFFFF0000u));
  }
  __syncthreads();

  // ---- Phase A: bf16 MFMA GEMM, both row-halves per wave ----
  const int lane64 = t & 63;
  const int wv  = t >> 6;            // wave 0..7
  const int q   = lane64 >> 4;       // k-group 0..3
  const int r16 = lane64 & 15;
  const int tA  = (wv + (blockIdx.x & 7)) & 7;   // col-tile 0..7
  const bool heavy = tA < 5;                     // also owns tB = 8+tA
  const int tB  = 8 + tA;

  const f32x4 fz = {0.f, 0.f, 0.f, 0.f};
  f32x4 dA0, dA1, dB0, dB1;          // combined accs, live across barrier
  int i0, jo;                        // C-fragment labels (base row, col)
  {
    f32x4 mA0 = fz, sA0 = fz, mA1 = fz, sA1 = fz;  // tile A, rh0 / rh1
    f32x4 mB0 = fz, sB0 = fz, mB1 = fz, sB1 = fz;  // tile B

    const short* xr0 = &sm.xb[0][r16][0];
    const short* xr1 = &sm.xb[0][16 + r16][0];
    const int wlane = lane64 * 8;

#pragma unroll 1
    for (int c = 0; c < 8; ++c) {
      const int xo = c * 32 + q * 8;
      short8 a0 = *(const short8*)(xr0 + xo);
      short8 a1 = *(const short8*)(xr0 + XB_L + xo);
      short8 a2 = *(const short8*)(xr0 + 2 * XB_L + xo);
      short8 c0_ = *(const short8*)(xr1 + xo);
      short8 c1_ = *(const short8*)(xr1 + XB_L + xo);
      short8 c2_ = *(const short8*)(xr1 + 2 * XB_L + xo);
      {
        const int wi = (tA * 8 + c) * 512 + wlane;
        short8 w0 = *(const short8*)(Wb + wi);
        short8 w1 = *(const short8*)(Wb + WPLANE + wi);
        short8 w2 = *(const short8*)(Wb + 2 * WPLANE + wi);
        PROD8(a0,  a1,  a2,  w0, w1, w2, mA0, sA0);
        PROD8(c0_, c1_, c2_, w0, w1, w2, mA1, sA1);
      }
      if (heavy) {
        const int wi = (tB * 8 + c) * 512 + wlane;
        short8 w0 = *(const short8*)(Wb + wi);
        short8 w1 = *(const short8*)(Wb + WPLANE + wi);
        short8 w2 = *(const short8*)(Wb + 2 * WPLANE + wi);
        PROD8(a0,  a1,  a2,  w0, w1, w2, mB0, sB0);
        PROD8(c0_, c1_, c2_, w0, w1, w2, mB1, sB1);
      }
    }

    // ---- layout probes: D=i (row labels) and D=j (col labels) ----
    // 16x16x32 C/D: col = lane&15, row = (lane>>4)*4 + reg (m89-verified,
    // regs = consecutive rows). Probes discover base row + col at runtime.
    short8 pa = {0, 0, 0, 0, 0, 0, 0, 0};
    short8 pb = {0, 0, 0, 0, 0, 0, 0, 0};
    if (q == 0) {
      pa[0] = (short)(__float_as_uint((float)r16) >> 16);  // bf16(r16), exact
      pb[0] = (short)0x3F80;                               // bf16(1.0)
    }
    f32x4 pr = MFMA_BF16(pa, pb, fz);   // D[i][*] = i
    f32x4 pc = MFMA_BF16(pb, pa, fz);   // D[*][j] = j
    i0 = ((int)(pr[0] + 0.5f)) & 15;    // base row of this lane's 4 regs
    jo = ((int)(pc[0] + 0.5f)) & 15;    // within-tile col

    dA0 = mA0 + sA0; dA1 = mA1 + sA1;
    dB0 = mB0 + sB0; dB1 = mB1 + sB1;
  }
  __syncthreads();   // all xb reads done; slab now owned by gpow/lgT

  // ---- Phase B: lgT stores (b128, transposed) + gumbels ----
  {
    const int cA = tA * 16 + jo;
    float bpA = bp[cA];
    float4 v0, v1;
    v0.x = dA0[0] + bpA; v0.y = dA0[1] + bpA; v0.z = dA0[2] + bpA; v0.w = dA0[3] + bpA;
    v1.x = dA1[0] + bpA; v1.y = dA1[1] + bpA; v1.z = dA1[2] + bpA; v1.w = dA1[3] + bpA;
    *(float4*)&sm.c.lgT[cA][i0]      = v0;   // rows i0..i0+3
    *(float4*)&sm.c.lgT[cA][16 + i0] = v1;   // rows 16+i0..
    if (heavy) {
      const int cB = tB * 16 + jo;
      float bpB = bp[cB];
      v0.x = dB0[0] + bpB; v0.y = dB0[1] + bpB; v0.z = dB0[2] + bpB; v0.w = dB0[3] + bpB;
      v1.x = dB1[0] + bpB; v1.y = dB1[1] + bpB; v1.z = dB1[2] + bpB; v1.w = dB1[3] + bpB;
      *(float4*)&sm.c.lgT[cB][i0]      = v0;
      *(float4*)&sm.c.lgT[cB][16 + i0] = v1;
    }
  }

  // pow gumbels: 32 rows x 80, 5 per thread; magic-mul div.
#pragma unroll
  for (int i = 0; i < 5; ++i) {
    int flat = t + 512 * i;                       // [0, 2560)
    int prw  = (flat * 13108) >> 20;              // flat / 80
    int q80  = flat - prw * 80;
    unsigned cnt = (unsigned)((b0 + prw) * 80 + q80);
    TF2 r = tf2(PK0, PK1, 0u, cnt);
    sm.c.gpow[prw][q80] = gumbelf(r.a ^ r.b);
  }

  // sc gumbels straight into registers (generator thread == consumer).
  float gsc[8];
  {
    const int prow = t >> 4;           // 0..31
    const int pn   = t & 15;           // category
    const unsigned cnt = (unsigned)((b0 + prow) * 16 + pn);
#pragma unroll
    for (int u = 0; u < 8; ++u) {
      TF2 r = tf2(SK0c[u], SK1c[u], 0u, cnt);
      gsc[u] = gumbelf(r.a ^ r.b);
    }
  }
  __syncthreads();

  // ---- Phase C: sampling. 16 lanes per row, DPP reduce trees. ----
  const int row  = t >> 4;               // 0..31
  const int lane = t & 15;
  const int g16  = (t & 63) >> 4;        // 16-lane group within wave
  const int shamt = g16 * 16;
  const int gb   = b0 + row;
  const int av = avail[gb * 16 + lane];
  const unsigned avm = (unsigned)((__ballot(av > 0) >> shamt) & 0xFFFFull);
  int stat = 0;
  float lpsum = 0.0f;
  float my_act = 0.0f;

  // sc scan: 8 users, sequential (sc_stat dependency)
#pragma unroll
  for (int u = 0; u < 8; ++u) {
    float logit = sm.c.lgT[u * 26 + lane][row];
    float ml = (stat < 2) ? logit : -1e10f;
    float y  = ml + gsc[u];
    float vmax = redmax16(y);                       // exact max, all lanes
    unsigned long long bal = __ballot(y == vmax);
    int idx = __builtin_ctz((unsigned)((bal >> shamt) & 0xFFFFull));
    float s = redsum16(__expf(ml));                 // softmax denom (no shift)
    float mlidx = redmax16((lane == idx) ? ml : -3.0e38f);  // broadcast ml[idx]
    float lp = mlidx - __logf(s);
    int au = (int)((avm >> u) & 1u);
    if (au) {
      lpsum += lp;
      if (lane == idx) stat += 1;
    }
    if (lane == u) my_act = au ? (float)idx : -1.0f;
  }

  // pow heads: independent
#pragma unroll
  for (int h = 0; h < 8; ++h) {
    bool on = lane < 10;
    float logit = on ? sm.c.lgT[h * 26 + 16 + lane][row] : -3.0e38f;
    float y     = on ? (logit + sm.c.gpow[row][h * 10 + lane]) : -3.0e38f;
    float vmax = redmax16(y);
    unsigned long long bal = __ballot(y == vmax);
    int idx = __builtin_ctz((unsigned)((bal >> shamt) & 0xFFFFull));
    float s = redsum16(on ? __expf(logit) : 0.0f);
    float mlidx = redmax16((lane == idx) ? logit : -3.0e38f);
    float lp = mlidx - __logf(s);
    int ah = (int)((avm >> (8 + h)) & 1u);
    if (ah) lpsum += lp;
    if (lane == 8 + h) my_act = ah ? (float)idx : -1.0f;
  }

  // ---- stores (all float32) ----
  out[(size_t)gb * 16 + lane] = my_act;                                // actions
  if (lane == 0) out[(size_t)B_TOTAL * 16 + gb] = lpsum;               // logp sum
  out[(size_t)B_TOTAL * 17 + (size_t)gb * 16 + lane] = (float)av;      // avail
}

extern "C" void kernel_launch(void* const* d_in, const int* in_sizes, int n_in,
                              void* d_out, int out_size, void* d_ws, size_t ws_size,
                              hipStream_t stream) {
  const float* x    = (const float*)d_in[0];
  const int*   av   = (const int*)  d_in[1];
  const float* Wsc  = (const float*)d_in[2];
  const float* bsc  = (const float*)d_in[3];
  const float* Wpow = (const float*)d_in[4];
  const float* bpow = (const float*)d_in[5];
  float* outp = (float*)d_out;

  float* bp = (float*)d_ws;                       // 256 floats
  short* Wb = (short*)((char*)d_ws + 1024);       // 3 * 53248 shorts (~312 KB)

  repack_kernel<<<209, 256, 0, stream>>>(Wsc, bsc, Wpow, bpow, Wb, bp);
  act_kernel<<<B_TOTAL / ROWS, 512, 0, stream>>>(x, av, Wb, bp, outp);
}

// Round 4
// 368.570 us; speedup vs baseline: 1.0289x; 1.0289x over previous
//
#include <hip/hip_runtime.h>

// ---------------------------------------------------------------------------
// MultiDiscreteACTLayer: B=131072 rows, D=256.
// Per row: 8 users x 16 sc logits + 8 heads x 10 pow logits = 208 dots of 256.
// JAX threefry, PARTITIONABLE semantics (jax>=0.4.36 default):
//   split(key,8)[u] = threefry2x32(key, (0, u))          (foldlike, both words)
//   fold_in(key, d) = threefry2x32(key, (0, d))          (both words)
//   random_bits 32-bit, element i: (b1,b2)=tf2(key,(0,i)); bits = b1 ^ b2
// Output (float32): actions (B,16) | logp_sum (B,1) | avail (B,16).
// R12 (from R11): remove the launch-bounds-induced spill regression.
//   - __launch_bounds__(512,6) had squeezed the allocator to 40 VGPRs ->
//     ~5 dwords/thread scratch spill (WRITE_SIZE 16.9->57.3 MB) around the
//     MFMA K-loop, cancelling the 60%-occupancy win. Back to (512,4): R10
//     measured 52 VGPR spill-free; 52 <= 85 keeps 6 waves/SIMD (3 blocks/CU,
//     LDS 50688) purely via actual resource usage.
//   - avail load issued before Phase A (latency hidden under MFMA loop).
//   Everything else identical to R11: 50.7KB LDS (gpow+lgT alias the dead
//   x-limb slab), transposed b128 logit stores, DPP Phase C, bf16 3-limb
//   GEMM, fp64 gumbel path.
// ---------------------------------------------------------------------------

#define B_TOTAL 131072
#define NCOL    208      // 8 users * (16 sc + 10 pow)
#define ROWS    32       // rows per block
#define TINYF   1.17549435e-38f

// W limb plane geometry (shorts): per (tile,chunk) 512, per tile 8*512=4096,
// per plane 13*4096 = 53248. Three planes.
#define WPLANE  53248
#define XB_L    8448     // x limb stride in shorts: 32 rows * 264 pitch
#define XB_P    264      // x row pitch in shorts (16B-aligned, bank-spread)
#define LGP     36       // lgT row pitch in floats (32 rows + pad)

typedef float f32x4 __attribute__((ext_vector_type(4)));
typedef short short8 __attribute__((ext_vector_type(8)));

#define MFMA_BF16(A,B,C) __builtin_amdgcn_mfma_f32_16x16x32_bf16((A),(B),(C),0,0,0)

// DPP row_ror within 16-lane rows (gfx9+ DPP row = 16 lanes).
// ctrl 0x120|n = row_ror:n. Full exec everywhere -> bound_ctrl false, old=src.
#define ROR16(v, n) __uint_as_float((unsigned)__builtin_amdgcn_update_dpp(     \
    (int)__float_as_uint(v), (int)__float_as_uint(v), 0x120 | (n), 0xF, 0xF, false))

__device__ __forceinline__ float redmax16(float v) {
  v = fmaxf(v, ROR16(v, 8));
  v = fmaxf(v, ROR16(v, 4));
  v = fmaxf(v, ROR16(v, 2));
  v = fmaxf(v, ROR16(v, 1));
  return v;
}
__device__ __forceinline__ float redsum16(float v) {
  v += ROR16(v, 8);
  v += ROR16(v, 4);
  v += ROR16(v, 2);
  v += ROR16(v, 1);
  return v;
}

struct TF2 { unsigned a, b; };

__host__ __device__ constexpr unsigned rotl_(unsigned x, int r) {
  return (x << r) | (x >> (32 - r));
}

// Threefry-2x32, 20 rounds, exactly as JAX/Random123.
__host__ __device__ constexpr TF2 tf2(unsigned k0, unsigned k1, unsigned x0, unsigned x1) {
  unsigned ks0 = k0, ks1 = k1, ks2 = k0 ^ k1 ^ 0x1BD11BDAu;
  x0 += ks0; x1 += ks1;
  x0 += x1; x1 = rotl_(x1, 13); x1 ^= x0;
  x0 += x1; x1 = rotl_(x1, 15); x1 ^= x0;
  x0 += x1; x1 = rotl_(x1, 26); x1 ^= x0;
  x0 += x1; x1 = rotl_(x1,  6); x1 ^= x0;
  x0 += ks1; x1 += ks2 + 1u;
  x0 += x1; x1 = rotl_(x1, 17); x1 ^= x0;
  x0 += x1; x1 = rotl_(x1, 29); x1 ^= x0;
  x0 += x1; x1 = rotl_(x1, 16); x1 ^= x0;
  x0 += x1; x1 = rotl_(x1, 24); x1 ^= x0;
  x0 += ks2; x1 += ks0 + 2u;
  x0 += x1; x1 = rotl_(x1, 13); x1 ^= x0;
  x0 += x1; x1 = rotl_(x1, 15); x1 ^= x0;
  x0 += x1; x1 = rotl_(x1, 26); x1 ^= x0;
  x0 += x1; x1 = rotl_(x1,  6); x1 ^= x0;
  x0 += ks0; x1 += ks1 + 3u;
  x0 += x1; x1 = rotl_(x1, 17); x1 ^= x0;
  x0 += x1; x1 = rotl_(x1, 29); x1 ^= x0;
  x0 += x1; x1 = rotl_(x1, 16); x1 ^= x0;
  x0 += x1; x1 = rotl_(x1, 24); x1 ^= x0;
  x0 += ks1; x1 += ks2 + 4u;
  x0 += x1; x1 = rotl_(x1, 13); x1 ^= x0;
  x0 += x1; x1 = rotl_(x1, 15); x1 ^= x0;
  x0 += x1; x1 = rotl_(x1, 26); x1 ^= x0;
  x0 += x1; x1 = rotl_(x1,  6); x1 ^= x0;
  x0 += ks2; x1 += ks0 + 5u;
  return TF2{x0, x1};
}

// foldlike derivation from root key (0, 42) — all compile-time constants.
__host__ __device__ constexpr unsigned key_a(unsigned d) { return tf2(0u, 42u, 0u, d).a; }
__host__ __device__ constexpr unsigned key_b(unsigned d) { return tf2(0u, 42u, 0u, d).b; }

constexpr unsigned SK0c[8] = {
  key_a(0), key_a(1), key_a(2), key_a(3), key_a(4), key_a(5), key_a(6), key_a(7)
};
constexpr unsigned SK1c[8] = {
  key_b(0), key_b(1), key_b(2), key_b(3), key_b(4), key_b(5), key_b(6), key_b(7)
};
constexpr unsigned PK0 = key_a(999);
constexpr unsigned PK1 = key_b(999);

// Fast fp64 natural log, positive normal inputs. Range-reduce m to
// [sqrt(1/2), sqrt(2)); atanh series in z=(m-1)/(m+1), terms to 1/13
// (trunc ~3e-12 rel); reciprocal via rcp_f32 seed + 1 fp64 Newton
// (~1.4e-14 rel). Total err ~1e-12 — flip-probability analysis: safe.
__device__ __forceinline__ double dlog(double xd) {
  long long b = __double_as_longlong(xd);
  int e = (int)(b >> 52) - 1023;
  double m = __longlong_as_double((b & 0x000FFFFFFFFFFFFFLL) | 0x3FF0000000000000LL);
  if (m > 1.4142135623730951) { m *= 0.5; e += 1; }
  double mp1 = m + 1.0;
  double r = (double)__builtin_amdgcn_rcpf((float)mp1);
  r = fma(fma(-mp1, r, 1.0), r, r);          // 1 Newton: ~1.4e-14 rel
  double z  = (m - 1.0) * r;
  double z2 = z * z;
  double p = fma(z2, fma(z2, fma(z2, fma(z2, fma(z2,
              1.0/13.0, 1.0/11.0), 1.0/9.0), 1.0/7.0), 1.0/5.0), 1.0/3.0);
  double lm = fma(2.0 * z, z2 * p, 2.0 * z);
  return fma((double)e, 0.6931471805599453, lm);
}

// JAX gumbel from raw bits, fp32 bit-ops replicated; logs in fp64 (dlog).
__device__ __forceinline__ float gumbelf(unsigned bits) {
  float u = __uint_as_float((bits >> 9) | 0x3f800000u) - 1.0f;   // [0,1)
  u = u + TINYF;
  u = fmaxf(TINYF, u);
  double nl = -dlog((double)u);            // in (5.9e-8, 87.4] — normal
  return -(float)dlog(nl);
}

// ---------------------------------------------------------------------------
// Kernel 0: split W_sc (8,256,16) + W_pow (8,256,10) into 3 bf16 limb planes,
// fragment-ordered for the act kernel's per-lane dwordx4 loads:
//   plane l, short index (T*8 + c)*512 + lane*8 + j  holds limb_l of
//   W[k = c*32 + (lane>>4)*8 + j][col = T*16 + (lane&15)],  col = u*26 + n.
// Truncation split: w = l0 + l1 + l2 exactly (fp32 = 3x8 mantissa bits).
// Plus packed bias bp[256] (fp32).
// ---------------------------------------------------------------------------
__global__ void repack_kernel(const float* __restrict__ Wsc, const float* __restrict__ bsc,
                              const float* __restrict__ Wpow, const float* __restrict__ bpow,
                              short* __restrict__ Wb, float* __restrict__ bp) {
  int t = blockIdx.x * 256 + threadIdx.x;   // [0, 53504)
  if (t < 53248) {
    int j    = t & 7;
    int lane = (t >> 3) & 63;
    int c    = (t >> 9) & 7;
    int T    = t >> 12;                     // 0..12
    int k    = c * 32 + (lane >> 4) * 8 + j;
    int col  = T * 16 + (lane & 15);        // < 208
    int u = col / 26, n = col % 26;
    float w = (n < 16) ? Wsc[(u * 256 + k) * 16 + n]
                       : Wpow[(u * 256 + k) * 10 + (n - 16)];
    unsigned b0 = __float_as_uint(w) & 0xFFFF0000u;
    float f1 = w - __uint_as_float(b0);
    unsigned b1 = __float_as_uint(f1) & 0xFFFF0000u;
    float f2 = f1 - __uint_as_float(b1);
    unsigned b2 = __float_as_uint(f2) & 0xFFFF0000u;
    int idx = (T * 8 + c) * 512 + lane * 8 + j;
    Wb[idx]              = (short)(b0 >> 16);
    Wb[WPLANE + idx]     = (short)(b1 >> 16);
    Wb[2 * WPLANE + idx] = (short)(b2 >> 16);
  } else {
    int cc = t - 53248;                     // [0,256)
    float v = 0.f;
    if (cc < NCOL) {
      int u = cc / 26, n = cc % 26;
      v = (n < 16) ? bsc[u * 16 + n] : bpow[u * 10 + (n - 16)];
    }
    bp[cc] = v;
  }
}

// 8 limb products (drop x2*W2 ~2^-32): accM = x0W0, accS = 7 small terms.
#define PROD8(X0, X1, X2, W0, W1, W2, AM, AS) do {                      \
    AM = MFMA_BF16(X0, W0, AM);                                         \
    AS = MFMA_BF16(X1, W0, AS);                                         \
    AS = MFMA_BF16(X0, W1, AS);                                         \
    AS = MFMA_BF16(X1, W1, AS);                                         \
    AS = MFMA_BF16(X2, W0, AS);                                         \
    AS = MFMA_BF16(X0, W2, AS);                                         \
    AS = MFMA_BF16(X2, W1, AS);                                         \
    AS = MFMA_BF16(X1, W2, AS);                                         \
  } while (0)

// ---------------------------------------------------------------------------
// Main kernel: each block handles 32 consecutive rows, 512 threads / 8 waves.
// Phase A: bf16 MFMA 16x16x32, 3-limb lossless split. Wave wv owns col-tile
//          tA=(wv+blk)&7 and (if tA<5) tB=8+tA; computes BOTH row-halves per
//          tile. C/D labels via runtime MFMA probes; accs combined and held
//          across the xb-dead barrier.
// Phase B: lgT b128 stores + pow gumbels into the re-used x-limb slab;
//          sc gumbels straight into registers.
// Phase C: 16 lanes per row; DPP row_ror reduce trees; ballot argmax;
//          avail as one ballot bitmask; no-max-shift softmax (fp32 hw).
// ---------------------------------------------------------------------------
__global__ __launch_bounds__(512, 4) void act_kernel(
    const float* __restrict__ x, const int* __restrict__ avail,
    const short* __restrict__ Wb, const float* __restrict__ bp,
    float* __restrict__ out) {
  __shared__ __align__(16) union SMem {
    short xb[3][ROWS][XB_P];     // Phase A: bf16 limbs of x tile (50688 B)
    struct {
      float gpow[ROWS][80];      // pow gumbels (10240 B)
      float lgT[NCOL][LGP];      // logits, TRANSPOSED [col][row] (29952 B)
    } c;
  } sm;

  const int t = threadIdx.x;
  const int b0 = blockIdx.x * ROWS;

  // avail: issue the global load NOW; consumed in Phase C (latency hidden
  // under the MFMA loop). Same thread mapping as Phase C (row = t>>4).
  const int av = avail[(size_t)(b0 + (t >> 4)) * 16 + (t & 15)];

  // ---- load x tile (32 rows x 256) as float4, split into bf16 limbs ----
#pragma unroll
  for (int i = 0; i < 4; ++i) {
    int flat = t + 512 * i;            // float4 index, [0,2048)
    int r  = flat >> 6;                // 64 float4 per row
    int kq = flat & 63;
    float4 v = ((const float4*)(x + (size_t)(b0 + r) * 256))[kq];
    unsigned L0[4], L1[4], L2[4];
#pragma unroll
    for (int e = 0; e < 4; ++e) {
      float f = (&v.x)[e];
      unsigned h0 = __float_as_uint(f) & 0xFFFF0000u;
      float f1 = f - __uint_as_float(h0);
      unsigned h1 = __float_as_uint(f1) & 0xFFFF0000u;
      float f2 = f1 - __uint_as_float(h1);
      unsigned h2 = __float_as_uint(f2) & 0xFFFF0000u;
      L0[e] = h0; L1[e] = h1; L2[e] = h2;
    }
    int ks = 4 * kq;
    *(uint2*)&sm.xb[0][r][ks] =
        make_uint2((L0[0] >> 16) | (L0[1] & 0xFFFF0000u),
                   (L0[2] >> 16) | (L0[3] & 0xFFFF0000u));
    *(uint2*)&sm.xb[1][r][ks] =
        make_uint2((L1[0] >> 16) | (L1[1] & 0xFFFF0000u),
                   (L1[2] >> 16) | (L1[3] & 0xFFFF0000u));
    *(uint2*)&sm.xb[2][r][ks] =
        make_uint2((L2[0] >> 16) | (L2[1] & 0xFFFF0000u),
                   (L2[2] >> 16) | (L2[3] & 0xFFFF0000u));
  }
  __syncthreads();

  // ---- Phase A: bf16 MFMA GEMM, both row-halves per wave ----
  const int lane64 = t & 63;
  const int wv  = t >> 6;            // wave 0..7
  const int q   = lane64 >> 4;       // k-group 0..3
  const int r16 = lane64 & 15;
  const int tA  = (wv + (blockIdx.x & 7)) & 7;   // col-tile 0..7
  const bool heavy = tA < 5;                     // also owns tB = 8+tA
  const int tB  = 8 + tA;

  const f32x4 fz = {0.f, 0.f, 0.f, 0.f};
  f32x4 dA0, dA1, dB0, dB1;          // combined accs, live across barrier
  int i0, jo;                        // C-fragment labels (base row, col)
  {
    f32x4 mA0 = fz, sA0 = fz, mA1 = fz, sA1 = fz;  // tile A, rh0 / rh1
    f32x4 mB0 = fz, sB0 = fz, mB1 = fz, sB1 = fz;  // tile B

    const short* xr0 = &sm.xb[0][r16][0];
    const short* xr1 = &sm.xb[0][16 + r16][0];
    const int wlane = lane64 * 8;

#pragma unroll 1
    for (int c = 0; c < 8; ++c) {
      const int xo = c * 32 + q * 8;
      short8 a0 = *(const short8*)(xr0 + xo);
      short8 a1 = *(const short8*)(xr0 + XB_L + xo);
      short8 a2 = *(const short8*)(xr0 + 2 * XB_L + xo);
      short8 c0_ = *(const short8*)(xr1 + xo);
      short8 c1_ = *(const short8*)(xr1 + XB_L + xo);
      short8 c2_ = *(const short8*)(xr1 + 2 * XB_L + xo);
      {
        const int wi = (tA * 8 + c) * 512 + wlane;
        short8 w0 = *(const short8*)(Wb + wi);
        short8 w1 = *(const short8*)(Wb + WPLANE + wi);
        short8 w2 = *(const short8*)(Wb + 2 * WPLANE + wi);
        PROD8(a0,  a1,  a2,  w0, w1, w2, mA0, sA0);
        PROD8(c0_, c1_, c2_, w0, w1, w2, mA1, sA1);
      }
      if (heavy) {
        const int wi = (tB * 8 + c) * 512 + wlane;
        short8 w0 = *(const short8*)(Wb + wi);
        short8 w1 = *(const short8*)(Wb + WPLANE + wi);
        short8 w2 = *(const short8*)(Wb + 2 * WPLANE + wi);
        PROD8(a0,  a1,  a2,  w0, w1, w2, mB0, sB0);
        PROD8(c0_, c1_, c2_, w0, w1, w2, mB1, sB1);
      }
    }

    // ---- layout probes: D=i (row labels) and D=j (col labels) ----
    // 16x16x32 C/D: col = lane&15, row = (lane>>4)*4 + reg (m89-verified,
    // regs = consecutive rows). Probes discover base row + col at runtime.
    short8 pa = {0, 0, 0, 0, 0, 0, 0, 0};
    short8 pb = {0, 0, 0, 0, 0, 0, 0, 0};
    if (q == 0) {
      pa[0] = (short)(__float_as_uint((float)r16) >> 16);  // bf16(r16), exact
      pb[0] = (short)0x3F80;                               // bf16(1.0)
    }
    f32x4 pr = MFMA_BF16(pa, pb, fz);   // D[i][*] = i
    f32x4 pc = MFMA_BF16(pb, pa, fz);   // D[*][j] = j
    i0 = ((int)(pr[0] + 0.5f)) & 15;    // base row of this lane's 4 regs
    jo = ((int)(pc[0] + 0.5f)) & 15;    // within-tile col

    dA0 = mA0 + sA0; dA1 = mA1 + sA1;
    dB0 = mB0 + sB0; dB1 = mB1 + sB1;
  }
  __syncthreads();   // all xb reads done; slab now owned by gpow/lgT

  // ---- Phase B: lgT stores (b128, transposed) + gumbels ----
  {
    const int cA = tA * 16 + jo;
    float bpA = bp[cA];
    float4 v0, v1;
    v0.x = dA0[0] + bpA; v0.y = dA0[1] + bpA; v0.z = dA0[2] + bpA; v0.w = dA0[3] + bpA;
    v1.x = dA1[0] + bpA; v1.y = dA1[1] + bpA; v1.z = dA1[2] + bpA; v1.w = dA1[3] + bpA;
    *(float4*)&sm.c.lgT[cA][i0]      = v0;   // rows i0..i0+3
    *(float4*)&sm.c.lgT[cA][16 + i0] = v1;   // rows 16+i0..
    if (heavy) {
      const int cB = tB * 16 + jo;
      float bpB = bp[cB];
      v0.x = dB0[0] + bpB; v0.y = dB0[1] + bpB; v0.z = dB0[2] + bpB; v0.w = dB0[3] + bpB;
      v1.x = dB1[0] + bpB; v1.y = dB1[1] + bpB; v1.z = dB1[2] + bpB; v1.w = dB1[3] + bpB;
      *(float4*)&sm.c.lgT[cB][i0]      = v0;
      *(float4*)&sm.c.lgT[cB][16 + i0] = v1;
    }
  }

  // pow gumbels: 32 rows x 80, 5 per thread; magic-mul div.
#pragma unroll
  for (int i = 0; i < 5; ++i) {
    int flat = t + 512 * i;                       // [0, 2560)
    int prw  = (flat * 13108) >> 20;              // flat / 80
    int q80  = flat - prw * 80;
    unsigned cnt = (unsigned)((b0 + prw) * 80 + q80);
    TF2 r = tf2(PK0, PK1, 0u, cnt);
    sm.c.gpow[prw][q80] = gumbelf(r.a ^ r.b);
  }

  // sc gumbels straight into registers (generator thread == consumer).
  float gsc[8];
  {
    const int prow = t >> 4;           // 0..31
    const int pn   = t & 15;           // category
    const unsigned cnt = (unsigned)((b0 + prow) * 16 + pn);
#pragma unroll
    for (int u = 0; u < 8; ++u) {
      TF2 r = tf2(SK0c[u], SK1c[u], 0u, cnt);
      gsc[u] = gumbelf(r.a ^ r.b);
    }
  }
  __syncthreads();

  // ---- Phase C: sampling. 16 lanes per row, DPP reduce trees. ----
  const int row  = t >> 4;               // 0..31
  const int lane = t & 15;
  const int g16  = (t & 63) >> 4;        // 16-lane group within wave
  const int shamt = g16 * 16;
  const int gb   = b0 + row;
  const unsigned avm = (unsigned)((__ballot(av > 0) >> shamt) & 0xFFFFull);
  int stat = 0;
  float lpsum = 0.0f;
  float my_act = 0.0f;

  // sc scan: 8 users, sequential (sc_stat dependency)
#pragma unroll
  for (int u = 0; u < 8; ++u) {
    float logit = sm.c.lgT[u * 26 + lane][row];
    float ml = (stat < 2) ? logit : -1e10f;
    float y  = ml + gsc[u];
    float vmax = redmax16(y);                       // exact max, all lanes
    unsigned long long bal = __ballot(y == vmax);
    int idx = __builtin_ctz((unsigned)((bal >> shamt) & 0xFFFFull));
    float s = redsum16(__expf(ml));                 // softmax denom (no shift)
    float mlidx = redmax16((lane == idx) ? ml : -3.0e38f);  // broadcast ml[idx]
    float lp = mlidx - __logf(s);
    int au = (int)((avm >> u) & 1u);
    if (au) {
      lpsum += lp;
      if (lane == idx) stat += 1;
    }
    if (lane == u) my_act = au ? (float)idx : -1.0f;
  }

  // pow heads: independent
#pragma unroll
  for (int h = 0; h < 8; ++h) {
    bool on = lane < 10;
    float logit = on ? sm.c.lgT[h * 26 + 16 + lane][row] : -3.0e38f;
    float y     = on ? (logit + sm.c.gpow[row][h * 10 + lane]) : -3.0e38f;
    float vmax = redmax16(y);
    unsigned long long bal = __ballot(y == vmax);
    int idx = __builtin_ctz((unsigned)((bal >> shamt) & 0xFFFFull));
    float s = redsum16(on ? __expf(logit) : 0.0f);
    float mlidx = redmax16((lane == idx) ? logit : -3.0e38f);
    float lp = mlidx - __logf(s);
    int ah = (int)((avm >> (8 + h)) & 1u);
    if (ah) lpsum += lp;
    if (lane == 8 + h) my_act = ah ? (float)idx : -1.0f;
  }

  // ---- stores (all float32) ----
  out[(size_t)gb * 16 + lane] = my_act;                                // actions
  if (lane == 0) out[(size_t)B_TOTAL * 16 + gb] = lpsum;               // logp sum
  out[(size_t)B_TOTAL * 17 + (size_t)gb * 16 + lane] = (float)av;      // avail
}

extern "C" void kernel_launch(void* const* d_in, const int* in_sizes, int n_in,
                              void* d_out, int out_size, void* d_ws, size_t ws_size,
                              hipStream_t stream) {
  const float* x    = (const float*)d_in[0];
  const int*   av   = (const int*)  d_in[1];
  const float* Wsc  = (const float*)d_in[2];
  const float* bsc  = (const float*)d_in[3];
  const float* Wpow = (const float*)d_in[4];
  const float* bpow = (const float*)d_in[5];
  float* outp = (float*)d_out;

  float* bp = (float*)d_ws;                       // 256 floats
  short* Wb = (short*)((char*)d_ws + 1024);       // 3 * 53248 shorts (~312 KB)

  repack_kernel<<<209, 256, 0, stream>>>(Wsc, bsc, Wpow, bpow, Wb, bp);
  act_kernel<<<B_TOTAL / ROWS, 512, 0, stream>>>(x, av, Wb, bp, outp);
}

// Round 5
// 361.849 us; speedup vs baseline: 1.0480x; 1.0186x over previous
//
#include <hip/hip_runtime.h>

// ---------------------------------------------------------------------------
// MultiDiscreteACTLayer: B=131072 rows, D=256.
// Per row: 8 users x 16 sc logits + 8 heads x 10 pow logits = 208 dots of 256.
// JAX threefry, PARTITIONABLE semantics (jax>=0.4.36 default):
//   split(key,8)[u] = threefry2x32(key, (0, u))          (foldlike, both words)
//   fold_in(key, d) = threefry2x32(key, (0, d))          (both words)
//   random_bits 32-bit, element i: (b1,b2)=tf2(key,(0,i)); bits = b1 ^ b2
// Output (float32): actions (B,16) | logp_sum (B,1) | avail (B,16).
// R13 (from R12): kill the fp64-log VALU tax (kernel is VALU-bound: 84%
//   busy across 3 structurally different rounds at ~250us).
//   - Gumbels now computed with hw v_log_f32 (~12cy) instead of 2x fp64
//     dlog (~170cy). Near u=1 a 3-term log1p polynomial replaces hw log
//     (hw log2 abs err ~2^-21 would be relatively huge there). Fast-path
//     abs error <= ~4e-5.
//   - Per argmax decision: if >=2 lanes within THR=2e-3 of the max, the
//     16-lane group falls back to the exact fp64 path (__noinline__ cold
//     fn; ~1e-2 probability/decision). Decisions are therefore BIT-
//     IDENTICAL to R12: certain gaps can't flip under <=4e-5 error;
//     uncertain ones rerun the exact path. logp unchanged (uses ml only).
//   - dlog's fp64 constants move to the cold fn -> hot regs drop.
//   Everything else identical to R12.
// ---------------------------------------------------------------------------

#define B_TOTAL 131072
#define NCOL    208      // 8 users * (16 sc + 10 pow)
#define ROWS    32       // rows per block
#define TINYF   1.17549435e-38f
#define THRF    2.0e-3f  // certainty threshold on top-2 gap (bound ~4e-5)

// W limb plane geometry (shorts): per (tile,chunk) 512, per tile 8*512=4096,
// per plane 13*4096 = 53248. Three planes.
#define WPLANE  53248
#define XB_L    8448     // x limb stride in shorts: 32 rows * 264 pitch
#define XB_P    264      // x row pitch in shorts (16B-aligned, bank-spread)
#define LGP     36       // lgT row pitch in floats (32 rows + pad)

typedef float f32x4 __attribute__((ext_vector_type(4)));
typedef short short8 __attribute__((ext_vector_type(8)));

#define MFMA_BF16(A,B,C) __builtin_amdgcn_mfma_f32_16x16x32_bf16((A),(B),(C),0,0,0)

// DPP row_ror within 16-lane rows (gfx9+ DPP row = 16 lanes).
// ctrl 0x120|n = row_ror:n. Full exec everywhere -> bound_ctrl false, old=src.
#define ROR16(v, n) __uint_as_float((unsigned)__builtin_amdgcn_update_dpp(     \
    (int)__float_as_uint(v), (int)__float_as_uint(v), 0x120 | (n), 0xF, 0xF, false))

__device__ __forceinline__ float redmax16(float v) {
  v = fmaxf(v, ROR16(v, 8));
  v = fmaxf(v, ROR16(v, 4));
  v = fmaxf(v, ROR16(v, 2));
  v = fmaxf(v, ROR16(v, 1));
  return v;
}
__device__ __forceinline__ float redsum16(float v) {
  v += ROR16(v, 8);
  v += ROR16(v, 4);
  v += ROR16(v, 2);
  v += ROR16(v, 1);
  return v;
}

struct TF2 { unsigned a, b; };

__host__ __device__ constexpr unsigned rotl_(unsigned x, int r) {
  return (x << r) | (x >> (32 - r));
}

// Threefry-2x32, 20 rounds, exactly as JAX/Random123.
__host__ __device__ constexpr TF2 tf2(unsigned k0, unsigned k1, unsigned x0, unsigned x1) {
  unsigned ks0 = k0, ks1 = k1, ks2 = k0 ^ k1 ^ 0x1BD11BDAu;
  x0 += ks0; x1 += ks1;
  x0 += x1; x1 = rotl_(x1, 13); x1 ^= x0;
  x0 += x1; x1 = rotl_(x1, 15); x1 ^= x0;
  x0 += x1; x1 = rotl_(x1, 26); x1 ^= x0;
  x0 += x1; x1 = rotl_(x1,  6); x1 ^= x0;
  x0 += ks1; x1 += ks2 + 1u;
  x0 += x1; x1 = rotl_(x1, 17); x1 ^= x0;
  x0 += x1; x1 = rotl_(x1, 29); x1 ^= x0;
  x0 += x1; x1 = rotl_(x1, 16); x1 ^= x0;
  x0 += x1; x1 = rotl_(x1, 24); x1 ^= x0;
  x0 += ks2; x1 += ks0 + 2u;
  x0 += x1; x1 = rotl_(x1, 13); x1 ^= x0;
  x0 += x1; x1 = rotl_(x1, 15); x1 ^= x0;
  x0 += x1; x1 = rotl_(x1, 26); x1 ^= x0;
  x0 += x1; x1 = rotl_(x1,  6); x1 ^= x0;
  x0 += ks0; x1 += ks1 + 3u;
  x0 += x1; x1 = rotl_(x1, 17); x1 ^= x0;
  x0 += x1; x1 = rotl_(x1, 29); x1 ^= x0;
  x0 += x1; x1 = rotl_(x1, 16); x1 ^= x0;
  x0 += x1; x1 = rotl_(x1, 24); x1 ^= x0;
  x0 += ks1; x1 += ks2 + 4u;
  x0 += x1; x1 = rotl_(x1, 13); x1 ^= x0;
  x0 += x1; x1 = rotl_(x1, 15); x1 ^= x0;
  x0 += x1; x1 = rotl_(x1, 26); x1 ^= x0;
  x0 += x1; x1 = rotl_(x1,  6); x1 ^= x0;
  x0 += ks2; x1 += ks0 + 5u;
  return TF2{x0, x1};
}

// foldlike derivation from root key (0, 42) — all compile-time constants.
__host__ __device__ constexpr unsigned key_a(unsigned d) { return tf2(0u, 42u, 0u, d).a; }
__host__ __device__ constexpr unsigned key_b(unsigned d) { return tf2(0u, 42u, 0u, d).b; }

constexpr unsigned SK0c[8] = {
  key_a(0), key_a(1), key_a(2), key_a(3), key_a(4), key_a(5), key_a(6), key_a(7)
};
constexpr unsigned SK1c[8] = {
  key_b(0), key_b(1), key_b(2), key_b(3), key_b(4), key_b(5), key_b(6), key_b(7)
};
constexpr unsigned PK0 = key_a(999);
constexpr unsigned PK1 = key_b(999);

// Fast fp64 natural log, positive normal inputs. Range-reduce m to
// [sqrt(1/2), sqrt(2)); atanh series in z=(m-1)/(m+1), terms to 1/13
// (trunc ~3e-12 rel); reciprocal via rcp_f32 seed + 1 fp64 Newton
// (~1.4e-14 rel). Total err ~1e-12 — flip-probability analysis: safe.
__device__ __forceinline__ double dlog(double xd) {
  long long b = __double_as_longlong(xd);
  int e = (int)(b >> 52) - 1023;
  double m = __longlong_as_double((b & 0x000FFFFFFFFFFFFFLL) | 0x3FF0000000000000LL);
  if (m > 1.4142135623730951) { m *= 0.5; e += 1; }
  double mp1 = m + 1.0;
  double r = (double)__builtin_amdgcn_rcpf((float)mp1);
  r = fma(fma(-mp1, r, 1.0), r, r);          // 1 Newton: ~1.4e-14 rel
  double z  = (m - 1.0) * r;
  double z2 = z * z;
  double p = fma(z2, fma(z2, fma(z2, fma(z2, fma(z2,
              1.0/13.0, 1.0/11.0), 1.0/9.0), 1.0/7.0), 1.0/5.0), 1.0/3.0);
  double lm = fma(2.0 * z, z2 * p, 2.0 * z);
  return fma((double)e, 0.6931471805599453, lm);
}

// JAX gumbel from raw bits, fp32 bit-ops replicated; logs in fp64 (dlog).
__device__ __forceinline__ float gumbelf(unsigned bits) {
  float u = __uint_as_float((bits >> 9) | 0x3f800000u) - 1.0f;   // [0,1)
  u = u + TINYF;
  u = fmaxf(TINYF, u);
  double nl = -dlog((double)u);            // in (5.9e-8, 87.4] — normal
  return -(float)dlog(nl);
}

// COLD path: exact gumbel (threefry + fp64 logs), one copy, called only
// when an argmax decision is uncertain (top-2 gap < THRF). Keeps the ~10
// fp64 dlog constants out of the hot path's register file.
__device__ __attribute__((noinline)) float gumbel_precise(unsigned k0, unsigned k1,
                                                          unsigned cnt) {
  TF2 r = tf2(k0, k1, 0u, cnt);
  return gumbelf(r.a ^ r.b);
}

// HOT path: hw v_log_f32 gumbel. Abs error <= ~4e-5 (vs exact):
//  - u <= 0.9921875: nl = -__logf(u), hw log2 abs err ~2^-21 -> rel err of
//    nl <= 2^-21*ln2/nl <= ~9e-5/nl... bounded by nl >= 7.8e-3 -> <= 1.3e-4?
//    (realistic hw 2^-22: <= 4e-5). Second log adds ~1e-7 abs.
//  - u > 0.9921875 (|t|<2^-7, t = u-1 exact): -log1p(t) via 3-term poly,
//    rel err <= |t|^3/4 ~ 1.2e-7.
// THRF = 2e-3 gives >= 15x margin over the pessimistic bound.
__device__ __forceinline__ float gumbel_fast(unsigned bits) {
  float u = __uint_as_float((bits >> 9) | 0x3f800000u) - 1.0f;   // [0,1)
  u = fmaxf(TINYF, u + TINYF);
  float t = u - 1.0f;                         // exact for u in [0.5, 1)
  float q  = fmaf(t, 0.33333333f, -0.5f);     // t/3 - 1/2
  float pl = -t * fmaf(t, q, 1.0f);           // -(t - t^2/2 + t^3/3)
  float hw = -__logf(u);
  float nl = (t > -0.0078125f) ? pl : hw;
  return -__logf(nl);
}

// ---------------------------------------------------------------------------
// Kernel 0: split W_sc (8,256,16) + W_pow (8,256,10) into 3 bf16 limb planes,
// fragment-ordered for the act kernel's per-lane dwordx4 loads:
//   plane l, short index (T*8 + c)*512 + lane*8 + j  holds limb_l of
//   W[k = c*32 + (lane>>4)*8 + j][col = T*16 + (lane&15)],  col = u*26 + n.
// Truncation split: w = l0 + l1 + l2 exactly (fp32 = 3x8 mantissa bits).
// Plus packed bias bp[256] (fp32).
// ---------------------------------------------------------------------------
__global__ void repack_kernel(const float* __restrict__ Wsc, const float* __restrict__ bsc,
                              const float* __restrict__ Wpow, const float* __restrict__ bpow,
                              short* __restrict__ Wb, float* __restrict__ bp) {
  int t = blockIdx.x * 256 + threadIdx.x;   // [0, 53504)
  if (t < 53248) {
    int j    = t & 7;
    int lane = (t >> 3) & 63;
    int c    = (t >> 9) & 7;
    int T    = t >> 12;                     // 0..12
    int k    = c * 32 + (lane >> 4) * 8 + j;
    int col  = T * 16 + (lane & 15);        // < 208
    int u = col / 26, n = col % 26;
    float w = (n < 16) ? Wsc[(u * 256 + k) * 16 + n]
                       : Wpow[(u * 256 + k) * 10 + (n - 16)];
    unsigned b0 = __float_as_uint(w) & 0xFFFF0000u;
    float f1 = w - __uint_as_float(b0);
    unsigned b1 = __float_as_uint(f1) & 0xFFFF0000u;
    float f2 = f1 - __uint_as_float(b1);
    unsigned b2 = __float_as_uint(f2) & 0xFFFF0000u;
    int idx = (T * 8 + c) * 512 + lane * 8 + j;
    Wb[idx]              = (short)(b0 >> 16);
    Wb[WPLANE + idx]     = (short)(b1 >> 16);
    Wb[2 * WPLANE + idx] = (short)(b2 >> 16);
  } else {
    int cc = t - 53248;                     // [0,256)
    float v = 0.f;
    if (cc < NCOL) {
      int u = cc / 26, n = cc % 26;
      v = (n < 16) ? bsc[u * 16 + n] : bpow[u * 10 + (n - 16)];
    }
    bp[cc] = v;
  }
}

// 8 limb products (drop x2*W2 ~2^-32): accM = x0W0, accS = 7 small terms.
#define PROD8(X0, X1, X2, W0, W1, W2, AM, AS) do {                      \
    AM = MFMA_BF16(X0, W0, AM);                                         \
    AS = MFMA_BF16(X1, W0, AS);                                         \
    AS = MFMA_BF16(X0, W1, AS);                                         \
    AS = MFMA_BF16(X1, W1, AS);                                         \
    AS = MFMA_BF16(X2, W0, AS);                                         \
    AS = MFMA_BF16(X0, W2, AS);                                         \
    AS = MFMA_BF16(X2, W1, AS);                                         \
    AS = MFMA_BF16(X1, W2, AS);                                         \
  } while (0)

// ---------------------------------------------------------------------------
// Main kernel: each block handles 32 consecutive rows, 512 threads / 8 waves.
// Phase A: bf16 MFMA 16x16x32, 3-limb lossless split. Wave wv owns col-tile
//          tA=(wv+blk)&7 and (if tA<5) tB=8+tA; computes BOTH row-halves per
//          tile. C/D labels via runtime MFMA probes; accs combined and held
//          across the xb-dead barrier.
// Phase B: lgT b128 stores + pow gumbels into the re-used x-limb slab;
//          sc gumbels straight into registers. All gumbels via gumbel_fast.
// Phase C: 16 lanes per row; DPP reduce trees; certainty ballot; cold
//          fp64 fallback for uncertain argmax groups (bit-identical to R12).
// ---------------------------------------------------------------------------
__global__ __launch_bounds__(512, 4) void act_kernel(
    const float* __restrict__ x, const int* __restrict__ avail,
    const short* __restrict__ Wb, const float* __restrict__ bp,
    float* __restrict__ out) {
  __shared__ __align__(16) union SMem {
    short xb[3][ROWS][XB_P];     // Phase A: bf16 limbs of x tile (50688 B)
    struct {
      float gpow[ROWS][80];      // pow gumbels (10240 B)
      float lgT[NCOL][LGP];      // logits, TRANSPOSED [col][row] (29952 B)
    } c;
  } sm;

  const int t = threadIdx.x;
  const int b0 = blockIdx.x * ROWS;

  // avail: issue the global load NOW; consumed in Phase C (latency hidden
  // under the MFMA loop). Same thread mapping as Phase C (row = t>>4).
  const int av = avail[(size_t)(b0 + (t >> 4)) * 16 + (t & 15)];

  // ---- load x tile (32 rows x 256) as float4, split into bf16 limbs ----
#pragma unroll
  for (int i = 0; i < 4; ++i) {
    int flat = t + 512 * i;            // float4 index, [0,2048)
    int r  = flat >> 6;                // 64 float4 per row
    int kq = flat & 63;
    float4 v = ((const float4*)(x + (size_t)(b0 + r) * 256))[kq];
    unsigned L0[4], L1[4], L2[4];
#pragma unroll
    for (int e = 0; e < 4; ++e) {
      float f = (&v.x)[e];
      unsigned h0 = __float_as_uint(f) & 0xFFFF0000u;
      float f1 = f - __uint_as_float(h0);
      unsigned h1 = __float_as_uint(f1) & 0xFFFF0000u;
      float f2 = f1 - __uint_as_float(h1);
      unsigned h2 = __float_as_uint(f2) & 0xFFFF0000u;
      L0[e] = h0; L1[e] = h1; L2[e] = h2;
    }
    int ks = 4 * kq;
    *(uint2*)&sm.xb[0][r][ks] =
        make_uint2((L0[0] >> 16) | (L0[1] & 0xFFFF0000u),
                   (L0[2] >> 16) | (L0[3] & 0xFFFF0000u));
    *(uint2*)&sm.xb[1][r][ks] =
        make_uint2((L1[0] >> 16) | (L1[1] & 0xFFFF0000u),
                   (L1[2] >> 16) | (L1[3] & 0xFFFF0000u));
    *(uint2*)&sm.xb[2][r][ks] =
        make_uint2((L2[0] >> 16) | (L2[1] & 0xFFFF0000u),
                   (L2[2] >> 16) | (L2[3] & 0xFFFF0000u));
  }
  __syncthreads();

  // ---- Phase A: bf16 MFMA GEMM, both row-halves per wave ----
  const int lane64 = t & 63;
  const int wv  = t >> 6;            // wave 0..7
  const int q   = lane64 >> 4;       // k-group 0..3
  const int r16 = lane64 & 15;
  const int tA  = (wv + (blockIdx.x & 7)) & 7;   // col-tile 0..7
  const bool heavy = tA < 5;                     // also owns tB = 8+tA
  const int tB  = 8 + tA;

  const f32x4 fz = {0.f, 0.f, 0.f, 0.f};
  f32x4 dA0, dA1, dB0, dB1;          // combined accs, live across barrier
  int i0, jo;                        // C-fragment labels (base row, col)
  {
    f32x4 mA0 = fz, sA0 = fz, mA1 = fz, sA1 = fz;  // tile A, rh0 / rh1
    f32x4 mB0 = fz, sB0 = fz, mB1 = fz, sB1 = fz;  // tile B

    const short* xr0 = &sm.xb[0][r16][0];
    const short* xr1 = &sm.xb[0][16 + r16][0];
    const int wlane = lane64 * 8;

#pragma unroll 1
    for (int c = 0; c < 8; ++c) {
      const int xo = c * 32 + q * 8;
      short8 a0 = *(const short8*)(xr0 + xo);
      short8 a1 = *(const short8*)(xr0 + XB_L + xo);
      short8 a2 = *(const short8*)(xr0 + 2 * XB_L + xo);
      short8 c0_ = *(const short8*)(xr1 + xo);
      short8 c1_ = *(const short8*)(xr1 + XB_L + xo);
      short8 c2_ = *(const short8*)(xr1 + 2 * XB_L + xo);
      {
        const int wi = (tA * 8 + c) * 512 + wlane;
        short8 w0 = *(const short8*)(Wb + wi);
        short8 w1 = *(const short8*)(Wb + WPLANE + wi);
        short8 w2 = *(const short8*)(Wb + 2 * WPLANE + wi);
        PROD8(a0,  a1,  a2,  w0, w1, w2, mA0, sA0);
        PROD8(c0_, c1_, c2_, w0, w1, w2, mA1, sA1);
      }
      if (heavy) {
        const int wi = (tB * 8 + c) * 512 + wlane;
        short8 w0 = *(const short8*)(Wb + wi);
        short8 w1 = *(const short8*)(Wb + WPLANE + wi);
        short8 w2 = *(const short8*)(Wb + 2 * WPLANE + wi);
        PROD8(a0,  a1,  a2,  w0, w1, w2, mB0, sB0);
        PROD8(c0_, c1_, c2_, w0, w1, w2, mB1, sB1);
      }
    }

    // ---- layout probes: D=i (row labels) and D=j (col labels) ----
    short8 pa = {0, 0, 0, 0, 0, 0, 0, 0};
    short8 pb = {0, 0, 0, 0, 0, 0, 0, 0};
    if (q == 0) {
      pa[0] = (short)(__float_as_uint((float)r16) >> 16);  // bf16(r16), exact
      pb[0] = (short)0x3F80;                               // bf16(1.0)
    }
    f32x4 pr = MFMA_BF16(pa, pb, fz);   // D[i][*] = i
    f32x4 pc = MFMA_BF16(pb, pa, fz);   // D[*][j] = j
    i0 = ((int)(pr[0] + 0.5f)) & 15;    // base row of this lane's 4 regs
    jo = ((int)(pc[0] + 0.5f)) & 15;    // within-tile col

    dA0 = mA0 + sA0; dA1 = mA1 + sA1;
    dB0 = mB0 + sB0; dB1 = mB1 + sB1;
  }
  __syncthreads();   // all xb reads done; slab now owned by gpow/lgT

  // ---- Phase B: lgT stores (b128, transposed) + gumbels ----
  {
    const int cA = tA * 16 + jo;
    float bpA = bp[cA];
    float4 v0, v1;
    v0.x = dA0[0] + bpA; v0.y = dA0[1] + bpA; v0.z = dA0[2] + bpA; v0.w = dA0[3] + bpA;
    v1.x = dA1[0] + bpA; v1.y = dA1[1] + bpA; v1.z = dA1[2] + bpA; v1.w = dA1[3] + bpA;
    *(float4*)&sm.c.lgT[cA][i0]      = v0;   // rows i0..i0+3
    *(float4*)&sm.c.lgT[cA][16 + i0] = v1;   // rows 16+i0..
    if (heavy) {
      const int cB = tB * 16 + jo;
      float bpB = bp[cB];
      v0.x = dB0[0] + bpB; v0.y = dB0[1] + bpB; v0.z = dB0[2] + bpB; v0.w = dB0[3] + bpB;
      v1.x = dB1[0] + bpB; v1.y = dB1[1] + bpB; v1.z = dB1[2] + bpB; v1.w = dB1[3] + bpB;
      *(float4*)&sm.c.lgT[cB][i0]      = v0;
      *(float4*)&sm.c.lgT[cB][16 + i0] = v1;
    }
  }

  // pow gumbels: 32 rows x 80, 5 per thread; magic-mul div. (fast path)
#pragma unroll
  for (int i = 0; i < 5; ++i) {
    int flat = t + 512 * i;                       // [0, 2560)
    int prw  = (flat * 13108) >> 20;              // flat / 80
    int q80  = flat - prw * 80;
    unsigned cnt = (unsigned)((b0 + prw) * 80 + q80);
    TF2 r = tf2(PK0, PK1, 0u, cnt);
    sm.c.gpow[prw][q80] = gumbel_fast(r.a ^ r.b);
  }

  // sc gumbels straight into registers (generator thread == consumer).
  float gsc[8];
  const unsigned cnt_sc = (unsigned)((b0 + (t >> 4)) * 16 + (t & 15));
#pragma unroll
  for (int u = 0; u < 8; ++u) {
    TF2 r = tf2(SK0c[u], SK1c[u], 0u, cnt_sc);
    gsc[u] = gumbel_fast(r.a ^ r.b);
  }
  __syncthreads();

  // ---- Phase C: sampling. 16 lanes per row, DPP reduce trees. ----
  const int row  = t >> 4;               // 0..31
  const int lane = t & 15;
  const int g16  = (t & 63) >> 4;        // 16-lane group within wave
  const int shamt = g16 * 16;
  const int gb   = b0 + row;
  const unsigned avm = (unsigned)((__ballot(av > 0) >> shamt) & 0xFFFFull);
  int stat = 0;
  float lpsum = 0.0f;
  float my_act = 0.0f;

  // sc scan: 8 users, sequential (sc_stat dependency)
#pragma unroll
  for (int u = 0; u < 8; ++u) {
    float logit = sm.c.lgT[u * 26 + lane][row];
    float ml = (stat < 2) ? logit : -1e10f;
    float y  = ml + gsc[u];
    float vmax = redmax16(y);
    // certainty ballot: lanes within THRF of max (includes the max lane)
    unsigned bal = (unsigned)((__ballot(vmax - y < THRF) >> shamt) & 0xFFFFull);
    int idx;
    if (__builtin_popcount(bal) > 1) {          // uncertain: exact replay
      float gp = gumbel_precise(SK0c[u], SK1c[u], cnt_sc);
      float yp = ml + gp;
      float vp = redmax16(yp);
      idx = __builtin_ctz((unsigned)((__ballot(yp == vp) >> shamt) & 0xFFFFull));
    } else {
      idx = __builtin_ctz(bal);
    }
    float s = redsum16(__expf(ml));                 // softmax denom (no shift)
    float mlidx = redmax16((lane == idx) ? ml : -3.0e38f);  // broadcast ml[idx]
    float lp = mlidx - __logf(s);
    int au = (int)((avm >> u) & 1u);
    if (au) {
      lpsum += lp;
      if (lane == idx) stat += 1;
    }
    if (lane == u) my_act = au ? (float)idx : -1.0f;
  }

  // pow heads: independent
#pragma unroll
  for (int h = 0; h < 8; ++h) {
    bool on = lane < 10;
    float logit = on ? sm.c.lgT[h * 26 + 16 + lane][row] : -3.0e38f;
    float y     = on ? (logit + sm.c.gpow[row][h * 10 + lane]) : -3.0e38f;
    float vmax = redmax16(y);
    unsigned bal = (unsigned)((__ballot(vmax - y < THRF) >> shamt) & 0xFFFFull);
    int idx;
    if (__builtin_popcount(bal) > 1) {          // uncertain: exact replay
      float gp = gumbel_precise(PK0, PK1, (unsigned)(gb * 80 + h * 10 + lane));
      float yp = on ? (logit + gp) : -3.0e38f;
      float vp = redmax16(yp);
      idx = __builtin_ctz((unsigned)((__ballot(yp == vp) >> shamt) & 0xFFFFull));
    } else {
      idx = __builtin_ctz(bal);
    }
    float s = redsum16(on ? __expf(logit) : 0.0f);
    float mlidx = redmax16((lane == idx) ? logit : -3.0e38f);
    float lp = mlidx - __logf(s);
    int ah = (int)((avm >> (8 + h)) & 1u);
    if (ah) lpsum += lp;
    if (lane == 8 + h) my_act = ah ? (float)idx : -1.0f;
  }

  // ---- stores (all float32) ----
  out[(size_t)gb * 16 + lane] = my_act;                                // actions
  if (lane == 0) out[(size_t)B_TOTAL * 16 + gb] = lpsum;               // logp sum
  out[(size_t)B_TOTAL * 17 + (size_t)gb * 16 + lane] = (float)av;      // avail
}

extern "C" void kernel_launch(void* const* d_in, const int* in_sizes, int n_in,
                              void* d_out, int out_size, void* d_ws, size_t ws_size,
                              hipStream_t stream) {
  const float* x    = (const float*)d_in[0];
  const int*   av   = (const int*)  d_in[1];
  const float* Wsc  = (const float*)d_in[2];
  const float* bsc  = (const float*)d_in[3];
  const float* Wpow = (const float*)d_in[4];
  const float* bpow = (const float*)d_in[5];
  float* outp = (float*)d_out;

  float* bp = (float*)d_ws;                       // 256 floats
  short* Wb = (short*)((char*)d_ws + 1024);       // 3 * 53248 shorts (~312 KB)

  repack_kernel<<<209, 256, 0, stream>>>(Wsc, bsc, Wpow, bpow, Wb, bp);
  act_kernel<<<B_TOTAL / ROWS, 512, 0, stream>>>(x, av, Wb, bp, outp);
}